// Round 1
// 219.165 us; speedup vs baseline: 1.0583x; 1.0583x over previous
//
#include <hip/hip_runtime.h>

typedef __bf16 bf16;
typedef __bf16 bf16x8 __attribute__((ext_vector_type(8)));
typedef float f32x4 __attribute__((ext_vector_type(4)));
typedef unsigned long long u64;

#define MFMA16(a, b, c) __builtin_amdgcn_mfma_f32_16x16x32_bf16(a, b, c, 0, 0, 0)

// Async global->LDS, 16 B/lane; LDS dest = wave-uniform base + lane*16.
__device__ __forceinline__ void gl_lds16(const void* g, void* l) {
  __builtin_amdgcn_global_load_lds(
      (const __attribute__((address_space(1))) unsigned int*)g,
      (__attribute__((address_space(3))) unsigned int*)l, 16, 0, 0);
}

// ---------------------------------------------------------------------------
// Fused prep:
//   blocks    0..1023: weight transpose+downcast (Wq,Wkv -> BqkvT; Wp -> WpT)
//   blocks 1024..1279: mask pack -> u64 bit-words
//   blocks 1280..3327: context f32 -> bf16 (cb)
//   blocks 3328..5375: x f32 -> bf16 (xb)   [NEW: lets QKV GEMM be all-async]
// ---------------------------------------------------------------------------
__global__ __launch_bounds__(256)
void prep_k(const float* __restrict__ Wq, const float* __restrict__ Wkv,
            const float* __restrict__ Wp, const int* __restrict__ mask,
            const float* __restrict__ context, const float* __restrict__ x,
            bf16* __restrict__ BqkvT, bf16* __restrict__ WpT,
            u64* __restrict__ maskbits, bf16* __restrict__ cb,
            bf16* __restrict__ xb) {
  const int bx = blockIdx.x;
  const int tid = threadIdx.x;
  if (bx >= 3328) {  // ---- x downcast
    const size_t i = ((size_t)(bx - 3328) * 256 + tid) * 8;
    f32x4 a0 = *(const f32x4*)(x + i);
    f32x4 a1 = *(const f32x4*)(x + i + 4);
    bf16x8 t;
#pragma unroll
    for (int j = 0; j < 4; ++j) { t[j] = (bf16)a0[j]; t[4 + j] = (bf16)a1[j]; }
    *(bf16x8*)(xb + i) = t;
    return;
  }
  if (bx >= 1280) {  // ---- context downcast
    const size_t i = ((size_t)(bx - 1280) * 256 + tid) * 8;
    f32x4 a0 = *(const f32x4*)(context + i);
    f32x4 a1 = *(const f32x4*)(context + i + 4);
    bf16x8 t;
#pragma unroll
    for (int j = 0; j < 4; ++j) { t[j] = (bf16)a0[j]; t[4 + j] = (bf16)a1[j]; }
    *(bf16x8*)(cb + i) = t;
    return;
  }
  if (bx >= 1024) {  // ---- mask pack
    const int idx = (bx - 1024) * 256 + tid;
    const int4* p = (const int4*)(mask + (size_t)idx * 64);
    u64 v = 0;
#pragma unroll
    for (int i = 0; i < 16; ++i) {
      int4 m = p[i];
      v |= (u64)(m.x != 0) << (4 * i);
      v |= (u64)(m.y != 0) << (4 * i + 1);
      v |= (u64)(m.z != 0) << (4 * i + 2);
      v |= (u64)(m.w != 0) << (4 * i + 3);
    }
    maskbits[idx] = v;
    return;
  }
  // ---- weight transpose tile
  const int ct = bx >> 4, rt = bx & 15;
  const float* src;
  bf16* dst;
  int C, c0, drow0;
  if (ct < 16) {
    src = Wq; C = 1024; c0 = ct * 64; dst = BqkvT; drow0 = c0;
  } else if (ct < 48) {
    src = Wkv; C = 2048; c0 = (ct - 16) * 64; dst = BqkvT; drow0 = 1024 + c0;
  } else {
    src = Wp; C = 1024; c0 = (ct - 48) * 64; dst = WpT; drow0 = c0;
  }
  __shared__ bf16 T[64][72];
  const int r0 = rt * 64;
#pragma unroll
  for (int i = 0; i < 2; ++i) {
    int c = i * 256 + tid;
    int row = c >> 3, col = (c & 7) * 8;
    const float* sp = &src[(size_t)(r0 + row) * C + c0 + col];
    f32x4 a0 = *(const f32x4*)sp;
    f32x4 a1 = *(const f32x4*)(sp + 4);
    bf16x8 t;
#pragma unroll
    for (int j = 0; j < 4; ++j) { t[j] = (bf16)a0[j]; t[4 + j] = (bf16)a1[j]; }
    *(bf16x8*)&T[row][col] = t;
  }
  __syncthreads();
#pragma unroll
  for (int i = 0; i < 2; ++i) {
    int c = i * 256 + tid;
    int orow = c >> 3, ocol = (c & 7) * 8;
    bf16x8 v;
#pragma unroll
    for (int j = 0; j < 8; ++j) v[j] = T[ocol + j][orow];
    *(bf16x8*)&dst[(size_t)(drow0 + orow) * 1024 + r0 + ocol] = v;
  }
}

// ---------------------------------------------------------------------------
// m97-structure GEMM: 128(M)xBN(N) tile, BK=64, single-buffered 2-barrier
// K-loop, all-bf16 async staging via global_load_lds (width 16), XOR-swizzled
// LDS (0 bank conflicts), 4 waves in 2x2 (each 64 x BN/2). LDS = 16+BN/4 KB
// -> 3 blocks/CU (VGPR-bound). XCD grid: blockIdx.x = m-block -> XCD = m%8.
//   EPI 1 (QKV): A = xb (q cols) / cb (kv cols). Scatters Q*SCALE2/K/V^T.
//   EPI 0 (OP):  A = aow, writes f32 out.
// ---------------------------------------------------------------------------
template <int EPI, int BN>
__global__ __launch_bounds__(256)
void gemm_sb(const bf16* __restrict__ A0, const bf16* __restrict__ A1,
             const bf16* __restrict__ Bt, const float* __restrict__ bias0,
             const float* __restrict__ bias1, bf16* __restrict__ oq,
             bf16* __restrict__ ok, bf16* __restrict__ ovt,
             float* __restrict__ outf) {
  constexpr int NJ = BN / 32;  // 16-wide n-frags per wave
  __shared__ bf16 As[128][64];
  __shared__ bf16 Bs[BN][64];
  const int tid = threadIdx.x;
  const int lane = tid & 63;
  const int w = tid >> 6;
  const int wm = (w >> 1) * 64;
  const int wn = (w & 1) * (BN / 2);
  const int l15 = lane & 15, l4 = lane >> 4;
  const int lrow = lane >> 3;
  const int scol = ((lane & 7) ^ (lrow & 7)) * 8;  // swizzled source column
  const int m0 = blockIdx.x * 128;  // m fastest -> XCD = m%8
  const int n0 = blockIdx.y * BN;

  const bf16* Asrc = (EPI == 1) ? ((n0 < 1024) ? A0 : A1) : A0;

  f32x4 acc[4][NJ] = {};

  for (int k = 0; k < 16; ++k) {
    const int kk = k * 64;
    // Stage A tile: 128 rows x 64 cols bf16; each wave 32 rows in 4 chunks.
#pragma unroll
    for (int it = 0; it < 4; ++it) {
      const int r = w * 32 + it * 8;
      gl_lds16(&Asrc[(size_t)(m0 + r + lrow) * 1024 + kk + scol], &As[r][0]);
    }
    // Stage B tile: BN rows x 64 cols.
#pragma unroll
    for (int it = 0; it < BN / 32; ++it) {
      const int r = w * (BN / 4) + it * 8;
      gl_lds16(&Bt[(size_t)(n0 + r + lrow) * 1024 + kk + scol], &Bs[r][0]);
    }
    __syncthreads();  // drains vmcnt (structural stall; covered by 3 blk/CU)
#pragma unroll
    for (int ks = 0; ks < 2; ++ks) {
      const int sw = ((ks * 4 + l4) ^ (l15 & 7)) * 8;
      bf16x8 af[4], bfr[NJ];
#pragma unroll
      for (int i = 0; i < 4; ++i)
        af[i] = *(const bf16x8*)&As[wm + i * 16 + l15][sw];
#pragma unroll
      for (int j = 0; j < NJ; ++j)
        bfr[j] = *(const bf16x8*)&Bs[wn + j * 16 + l15][sw];
#pragma unroll
      for (int i = 0; i < 4; ++i)
#pragma unroll
        for (int j = 0; j < NJ; ++j)
          acc[i][j] = MFMA16(af[i], bfr[j], acc[i][j]);
    }
    __syncthreads();  // LDS consumed; safe to overwrite next iter
  }

  const float SCALE2 = 0.18033688011112042f;  // 1/sqrt(64) * log2(e)
#pragma unroll
  for (int j = 0; j < NJ; ++j) {
    const int col = n0 + wn + j * 16 + l15;
    float bc;
    if (EPI == 1) bc = (col < 1024) ? bias0[col] : bias1[col - 1024];
    else bc = bias0[col];
#pragma unroll
    for (int i = 0; i < 4; ++i) {
#pragma unroll
      for (int r = 0; r < 4; ++r) {
        const int row = m0 + wm + i * 16 + l4 * 4 + r;
        const float v = acc[i][j][r] + bc;
        if (EPI == 0) {
          outf[(size_t)row * 1024 + col] = v;
        } else {
          const int b = row >> 10, n = row & 1023;
          if (col < 1024) {
            const int h = col >> 6, d = col & 63;
            oq[(((size_t)(b * 16 + h)) * 1024 + n) * 64 + d] =
                (bf16)(v * SCALE2);
          } else {
            const int ckv = col - 1024;
            const int s = ckv >> 10, c2 = ckv & 1023;
            const int h = c2 >> 6, d = c2 & 63;
            if (s == 0)
              ok[(((size_t)(b * 16 + h)) * 1024 + n) * 64 + d] = (bf16)v;
            else
              ovt[(((size_t)(b * 16 + h)) * 64 + d) * 1024 + n] = (bf16)v;
          }
        }
      }
    }
  }
}

// ---------------------------------------------------------------------------
// Flash-style masked attention, fixed-max softmax, bit-packed mask, XCD grid
// (bh fastest). Unchanged.
// ---------------------------------------------------------------------------
__global__ __launch_bounds__(256)
void attn_kernel(const bf16* __restrict__ q, const bf16* __restrict__ k,
                 const bf16* __restrict__ vT, const u64* __restrict__ maskbits,
                 bf16* __restrict__ ao) {
  const int bh = blockIdx.x;
  const int ntile = blockIdx.y;
  const int b = bh >> 4, h = bh & 15;
  const int tid = threadIdx.x;
  const int lane = tid & 63;
  const int w = tid >> 6;
  const int l15 = lane & 15, l4 = lane >> 4;

  __shared__ bf16 Ks[64][72];
  __shared__ bf16 Vts[64][72];
  __shared__ bf16 Pw[4][16][72];

  const size_t base = (size_t)bh * 65536;
  const int nrow0 = ntile * 64 + w * 16;

  bf16x8 qf[2];
#pragma unroll
  for (int ks = 0; ks < 2; ++ks)
    qf[ks] =
        *(const bf16x8*)&q[base + (size_t)(nrow0 + l15) * 64 + ks * 32 + l4 * 8];

  f32x4 o[4] = {};
  float lsum[4] = {0.0f, 0.0f, 0.0f, 0.0f};

  const u64* mb = maskbits + (size_t)(b * 1024 + nrow0) * 16;

  for (int mt = 0; mt < 16; ++mt) {
#pragma unroll
    for (int i = 0; i < 2; ++i) {
      int c = i * 256 + tid;
      int row = c >> 3, col = (c & 7) * 8;
      *(bf16x8*)&Ks[row][col] =
          *(const bf16x8*)&k[base + (size_t)(mt * 64 + row) * 64 + col];
      *(bf16x8*)&Vts[row][col] =
          *(const bf16x8*)&vT[base + (size_t)row * 1024 + mt * 64 + col];
    }
    __syncthreads();

    f32x4 s[4];
#pragma unroll
    for (int sub = 0; sub < 4; ++sub) s[sub] = f32x4{-12.f, -12.f, -12.f, -12.f};
#pragma unroll
    for (int ks = 0; ks < 2; ++ks) {
#pragma unroll
      for (int sub = 0; sub < 4; ++sub) {
        bf16x8 bfr = *(const bf16x8*)&Ks[sub * 16 + l15][ks * 32 + l4 * 8];
        s[sub] = MFMA16(qf[ks], bfr, s[sub]);
      }
    }

    u64 wbits[4];
#pragma unroll
    for (int r = 0; r < 4; ++r) wbits[r] = mb[(size_t)(l4 * 4 + r) * 16 + mt];

#pragma unroll
    for (int sub = 0; sub < 4; ++sub) {
#pragma unroll
      for (int r = 0; r < 4; ++r) {
        float p = exp2f(s[sub][r]);
        p = ((wbits[r] >> (sub * 16 + l15)) & 1) ? p : 0.0f;
        lsum[r] += p;
        Pw[w][l4 * 4 + r][sub * 16 + l15] = (bf16)p;
      }
    }

#pragma unroll
    for (int ks = 0; ks < 2; ++ks) {
      bf16x8 af = *(const bf16x8*)&Pw[w][l15][ks * 32 + l4 * 8];
#pragma unroll
      for (int sub = 0; sub < 4; ++sub) {
        bf16x8 bfr = *(const bf16x8*)&Vts[sub * 16 + l15][ks * 32 + l4 * 8];
        o[sub] = MFMA16(af, bfr, o[sub]);
      }
    }
    __syncthreads();
  }

  float inv[4];
#pragma unroll
  for (int r = 0; r < 4; ++r) {
    float t = lsum[r];
#pragma unroll
    for (int d = 1; d < 16; d <<= 1) t += __shfl_xor(t, d);
    inv[r] = 1.0f / t;
  }

#pragma unroll
  for (int sub = 0; sub < 4; ++sub) {
#pragma unroll
    for (int r = 0; r < 4; ++r) {
      const int n = nrow0 + l4 * 4 + r;
      const size_t idx =
          ((size_t)(b * 1024 + n)) * 1024 + h * 64 + sub * 16 + l15;
      ao[idx] = (bf16)(o[sub][r] * inv[r]);
    }
  }
}

// ---------------------------------------------------------------------------
extern "C" void kernel_launch(void* const* d_in, const int* in_sizes, int n_in,
                              void* d_out, int out_size, void* d_ws,
                              size_t ws_size, hipStream_t stream) {
  const float* x = (const float*)d_in[0];        // [4,1024,1024]
  const float* context = (const float*)d_in[1];  // [4,1024,1024]
  const int* mask = (const int*)d_in[2];         // [4,1024,32,32]
  const float* Wq = (const float*)d_in[3];
  const float* bq = (const float*)d_in[4];
  const float* Wkv = (const float*)d_in[5];
  const float* bkv = (const float*)d_in[6];
  const float* Wp = (const float*)d_in[7];
  const float* bp = (const float*)d_in[8];
  float* out = (float*)d_out;                    // [4,1024,1024] f32

  // Workspace (48.5 MB):
  //  @0    (8 MB): cb (prep->QKV), dead after QKV -> aow reuses it
  //  @8    (8 MB): xb (prep->QKV), dead after QKV
  //  @16   (6 MB): BqkvT (prep->QKV)
  //  @22   (8 MB): qw   @30 (8 MB): kw   @38 (8 MB): vtw
  //  @46 (0.5 MB): maskbits   @46.5 (2 MB): WpT
  char* ws = (char*)d_ws;
  bf16* cb = (bf16*)(ws);
  bf16* aow = (bf16*)(ws);
  bf16* xb = (bf16*)(ws + (8ull << 20));
  bf16* BqkvT = (bf16*)(ws + (16ull << 20));
  bf16* qw = (bf16*)(ws + (22ull << 20));
  bf16* kw = (bf16*)(ws + (30ull << 20));
  bf16* vtw = (bf16*)(ws + (38ull << 20));
  u64* maskbits = (u64*)(ws + (46ull << 20));
  bf16* WpT = (bf16*)(ws + (46ull << 20) + (512ull << 10));

  const dim3 blk(256);

  // Prep: weight transposes + mask pack + context/x downcast, one launch.
  prep_k<<<dim3(5376), blk, 0, stream>>>(Wq, Wkv, Wp, mask, context, x, BqkvT,
                                         WpT, maskbits, cb, xb);

  // Fused QKV projection: 128x128 m97-structure, grid (m=32, n=24), 3 blk/CU.
  gemm_sb<1, 128><<<dim3(32, 24), blk, 0, stream>>>(xb, cb, BqkvT, bq, bkv,
                                                    qw, kw, vtw, nullptr);

  // Attention: grid (bh=64, ntile=16) -> XCD = bh%8.
  attn_kernel<<<dim3(64, 16), blk, 0, stream>>>(qw, kw, vtw, maskbits, aow);

  // Output projection: 128x64 tiles, grid (m=32, n=16) -> 2 blk/CU.
  gemm_sb<0, 64><<<dim3(32, 16), blk, 0, stream>>>(aow, nullptr, WpT, bp,
                                                   nullptr, nullptr, nullptr,
                                                   nullptr, out);
}